// Round 10
// baseline (2609.402 us; speedup 1.0000x reference)
//
#include <hip/hip_runtime.h>

// Problem constants
#define B_ 32
#define S_ 2048
#define DA 32
#define DH 128
#define DS 64
#define DS2 4096

template <int CTRL>
__device__ __forceinline__ float dpp_add(float x) {
  int t = __builtin_amdgcn_update_dpp(0, __float_as_int(x), CTRL, 0xF, 0xF, true);
  return x + __int_as_float(t);
}
// sum over the 16 lanes of each row, result uniform within the row
__device__ __forceinline__ float row_sum16(float x) {
  x = dpp_add<0xB1>(x);   // xor1
  x = dpp_add<0x4E>(x);   // xor2
  x = dpp_add<0x141>(x);  // half-mirror
  x = dpp_add<0x140>(x);  // mirror
  return x;
}

// async global->LDS DMA, 16 B per lane (dest = wave-uniform base + lane*16)
__device__ __forceinline__ void gl2lds16(const float* g, float* l) {
  __builtin_amdgcn_global_load_lds(
      (const __attribute__((address_space(1))) void*)g,
      (__attribute__((address_space(3))) void*)l, 16, 0, 0);
}

// ---------------------------------------------------------------------------
// Kernel 1: h1t[f][tok] = relu(relu(actions@w0 + b0)@w1 + b1)  (TRANSPOSED out)
// ---------------------------------------------------------------------------
__global__ __launch_bounds__(256) void k_mlp01(
    const float* __restrict__ actions, const float* __restrict__ w0,
    const float* __restrict__ b0, const float* __restrict__ w1,
    const float* __restrict__ b1, float* __restrict__ h1t,
    int s_base, int M)
{
  __shared__ float a_t[DA][64];    // [k][tok]   8 KB
  __shared__ float w0_l[DA][DH];   // [k][f]    16 KB
  __shared__ float h0t[DH][64];    // [f][tok]  32 KB
  const int tid = threadIdx.x;
  const int m0 = blockIdx.x * 64;

#pragma unroll
  for (int q = 0; q < 2; ++q) {
    int g = tid + 256 * q;
    int tok = g >> 3, kq = g & 7;
    int tl = m0 + tok;
    int b = tl & 31, s = s_base + (tl >> 5);
    float4 v = *(const float4*)(actions + ((size_t)b * S_ + s) * DA + 4 * kq);
    a_t[4 * kq + 0][tok] = v.x; a_t[4 * kq + 1][tok] = v.y;
    a_t[4 * kq + 2][tok] = v.z; a_t[4 * kq + 3][tok] = v.w;
  }
#pragma unroll
  for (int q = 0; q < 4; ++q) {
    int g = tid + 256 * q;
    ((float4*)&w0_l[0][0])[g] = ((const float4*)w0)[g];
  }
  __syncthreads();

  const int tm = tid & 15;
  const int tn = tid >> 4;

  float acc[4][8];
#pragma unroll
  for (int mi = 0; mi < 4; ++mi)
#pragma unroll
    for (int ni = 0; ni < 8; ++ni) acc[mi][ni] = 0.f;

#pragma unroll 4
  for (int k = 0; k < DA; ++k) {
    float4 a4 = *(const float4*)&a_t[k][4 * tm];
    float4 wa = *(const float4*)&w0_l[k][8 * tn];
    float4 wb = *(const float4*)&w0_l[k][8 * tn + 4];
    float av[4] = {a4.x, a4.y, a4.z, a4.w};
    float wv[8] = {wa.x, wa.y, wa.z, wa.w, wb.x, wb.y, wb.z, wb.w};
#pragma unroll
    for (int mi = 0; mi < 4; ++mi)
#pragma unroll
      for (int ni = 0; ni < 8; ++ni) acc[mi][ni] += av[mi] * wv[ni];
  }
  {
    float4 ba = *(const float4*)(b0 + 8 * tn);
    float4 bb = *(const float4*)(b0 + 8 * tn + 4);
    float bv[8] = {ba.x, ba.y, ba.z, ba.w, bb.x, bb.y, bb.z, bb.w};
#pragma unroll
    for (int mi = 0; mi < 4; ++mi)
#pragma unroll
      for (int ni = 0; ni < 8; ++ni)
        h0t[8 * tn + ni][4 * tm + mi] = fmaxf(acc[mi][ni] + bv[ni], 0.f);
  }
  __syncthreads();

  float acc1[4][8];
#pragma unroll
  for (int mi = 0; mi < 4; ++mi)
#pragma unroll
    for (int ni = 0; ni < 8; ++ni) acc1[mi][ni] = 0.f;

#pragma unroll 4
  for (int k = 0; k < DH; ++k) {
    float4 h4 = *(const float4*)&h0t[k][4 * tm];
    float4 wa = *(const float4*)(w1 + (size_t)k * DH + 8 * tn);
    float4 wb = *(const float4*)(w1 + (size_t)k * DH + 8 * tn + 4);
    float av[4] = {h4.x, h4.y, h4.z, h4.w};
    float wv[8] = {wa.x, wa.y, wa.z, wa.w, wb.x, wb.y, wb.z, wb.w};
#pragma unroll
    for (int mi = 0; mi < 4; ++mi)
#pragma unroll
      for (int ni = 0; ni < 8; ++ni) acc1[mi][ni] += av[mi] * wv[ni];
  }
  {
    float4 ba = *(const float4*)(b1 + 8 * tn);
    float4 bb = *(const float4*)(b1 + 8 * tn + 4);
    float bv[8] = {ba.x, ba.y, ba.z, ba.w, bb.x, bb.y, bb.z, bb.w};
#pragma unroll
    for (int ni = 0; ni < 8; ++ni) {
      float4 o;
      o.x = fmaxf(acc1[0][ni] + bv[ni], 0.f);
      o.y = fmaxf(acc1[1][ni] + bv[ni], 0.f);
      o.z = fmaxf(acc1[2][ni] + bv[ni], 0.f);
      o.w = fmaxf(acc1[3][ni] + bv[ni], 0.f);
      *(float4*)(h1t + (size_t)(8 * tn + ni) * M + m0 + 4 * tm) = o;
    }
  }
}

// ---------------------------------------------------------------------------
// Kernel 2: trans = h1t^T @ w2 + b2.  (unchanged R6 design)
// ---------------------------------------------------------------------------
#define TKK 16
__global__ __launch_bounds__(256, 2) void k_trans(
    const float* __restrict__ h1t, const float* __restrict__ w2,
    const float* __restrict__ b2, float* __restrict__ trans, int M)
{
  __shared__ float As[2][TKK][128];  // 8 KB x2
  __shared__ float Bs[2][TKK][128];  // 8 KB x2
  const int tid = threadIdx.x;
  const int n0 = blockIdx.x * 128;
  const int m0 = blockIdx.y * 128;
  const int w  = tid >> 6;
  const int lw = tid & 63;

  auto aload = [&](int t, int buf) {
#pragma unroll
    for (int ii = 0; ii < 2; ++ii) {
      const int i = 2 * w + ii;
      const int kr = 2 * i + (lw >> 5);
      const int c4 = 4 * (lw & 31);
      gl2lds16(h1t + (size_t)(t * TKK + kr) * M + m0 + c4, &As[buf][2 * i][0]);
      gl2lds16(w2 + (size_t)(t * TKK + kr) * DS2 + n0 + c4, &Bs[buf][2 * i][0]);
    }
  };

  aload(0, 0);

  const int mg = tid >> 4;
  const int ng = tid & 15;
  float acc[8][8];
#pragma unroll
  for (int mi = 0; mi < 8; ++mi)
#pragma unroll
    for (int ni = 0; ni < 8; ++ni) acc[mi][ni] = 0.f;

  int buf = 0;
  for (int t = 0; t < DH / TKK; ++t) {
    __syncthreads();
    if (t < DH / TKK - 1) aload(t + 1, buf ^ 1);
#pragma unroll
    for (int k = 0; k < TKK; ++k) {
      float4 a0 = *(const float4*)&As[buf][k][8 * mg];
      float4 a1 = *(const float4*)&As[buf][k][8 * mg + 4];
      float av[8] = {a0.x, a0.y, a0.z, a0.w, a1.x, a1.y, a1.z, a1.w};
      float4 b0v = *(const float4*)&Bs[buf][k][4 * ng];
      float4 b1v = *(const float4*)&Bs[buf][k][64 + 4 * ng];
      float bv[8] = {b0v.x, b0v.y, b0v.z, b0v.w, b1v.x, b1v.y, b1v.z, b1v.w};
#pragma unroll
      for (int mi = 0; mi < 8; ++mi)
#pragma unroll
        for (int ni = 0; ni < 8; ++ni) acc[mi][ni] += av[mi] * bv[ni];
    }
    buf ^= 1;
  }

  float4 bb0 = *(const float4*)(b2 + n0 + 4 * ng);
  float4 bb1 = *(const float4*)(b2 + n0 + 64 + 4 * ng);
  float bv[8] = {bb0.x, bb0.y, bb0.z, bb0.w, bb1.x, bb1.y, bb1.z, bb1.w};
#pragma unroll
  for (int mi = 0; mi < 8; ++mi) {
    float* dst = trans + (size_t)(m0 + 8 * mg + mi) * DS2 + n0;
#pragma unroll
    for (int q = 0; q < 2; ++q) {
      float4 o;
      o.x = acc[mi][4 * q + 0] + bv[4 * q + 0];
      o.y = acc[mi][4 * q + 1] + bv[4 * q + 1];
      o.z = acc[mi][4 * q + 2] + bv[4 * q + 2];
      o.w = acc[mi][4 * q + 3] + bv[4 * q + 3];
      *(float4*)(dst + 64 * q + 4 * ng) = o;
    }
  }
}

// ---------------------------------------------------------------------------
// Kernel 3: RNN.  Grid = 256 blocks.
//  Blocks 0..31 : R8's validated consumer/producer LDS-ring recurrence for
//                 batch b = blockIdx (+ progress publication every 8 steps).
//  Blocks 32..255: PREFETCHERS — 7 per batch stream the chunk's trans into
//                 L2/LLC <=32 steps ahead of the consumer (throttled on
//                 progress[b]; bounded spin -> perf-only, cannot hang).
// Rationale: one CU's outstanding-request capacity caps streaming at ~24 GB/s
// (1/256 of chip) — R6 and R8 both measured exactly that wall.  224 extra CUs
// fetching turn consumer DMA misses (~900 cyc) into cache hits.
// ---------------------------------------------------------------------------
__global__ __launch_bounds__(256, 1) void k_rnn(
    const float* __restrict__ trans, const float* __restrict__ init_hidden,
    float* __restrict__ hstate, int* __restrict__ progress,
    float* __restrict__ out, int s_base, int SC, int chunk)
{
  const int tid = threadIdx.x;

  if (blockIdx.x >= 32) {
    // ---------------- prefetcher block ----------------
    const int k = (int)(blockIdx.x - 32) >> 3;   // 0..27
    const int x = (int)blockIdx.x & 7;           // nominal XCD
    const int pb_ = x + 8 * (k & 3);             // batch covered (0..31)
    const int r  = k >> 2;                       // step residue 0..6 (mod 7)
    const float* gbase = trans + (size_t)pb_ * DS2;
    float acc = 0.f;
    for (int s = r; s < SC; s += 7) {
      int spin = 0;
      for (;;) {
        int pr = __hip_atomic_load(&progress[pb_], __ATOMIC_RELAXED,
                                   __HIP_MEMORY_SCOPE_AGENT);
        if (s - pr <= 32) break;                 // close enough to consumer
        if (++spin > (1 << 13)) break;           // bounded: perf-only
        __builtin_amdgcn_s_sleep(8);
      }
      const float4* g = (const float4*)(gbase + (size_t)s * (32 * DS2)) + tid;
      acc += g[0].x + g[256].y + g[512].z + g[768].w;  // touch all 16 KB
    }
    if (acc == 1.2345e38f) out[0] = acc;  // never true; defeats DCE
    return;
  }

  // ---------------- consumer/producer block (R8, validated) ----------------
  __shared__ float4 ring[6][16][64];   // 96 KB
  __shared__ int flags[6];
  __shared__ int cons;
  const int wv = tid >> 6;
  const int lane = tid & 63;
  const int b = blockIdx.x;

  if (tid < 6) flags[tid] = 0;
  if (tid == 6) cons = 0;
  __syncthreads();

  const float* base = trans + (size_t)b * DS2;

  if (wv > 0) {
    // ---- producer: steps s ≡ wv-1 (mod 3) ----
    const int p = wv - 1;
    int prev = -1;
    for (int s = p; s < SC; s += 3) {
      while (s - __hip_atomic_load(&cons, __ATOMIC_RELAXED,
                                   __HIP_MEMORY_SCOPE_WORKGROUP) > 5)
        __builtin_amdgcn_s_sleep(2);
      const int slot = s % 6;
      const float* g = base + (size_t)s * (32 * DS2) + 4 * lane;
      float* l = (float*)&ring[slot][0][0];
#pragma unroll
      for (int q = 0; q < 16; ++q)
        gl2lds16(g + q * 256, l + q * 256);
      if (prev >= 0) {
        asm volatile("s_waitcnt vmcnt(16)" ::: "memory");
        __hip_atomic_store(&flags[prev % 6], prev + 1, __ATOMIC_RELAXED,
                           __HIP_MEMORY_SCOPE_WORKGROUP);
      }
      prev = s;
    }
    if (prev >= 0) {
      asm volatile("s_waitcnt vmcnt(0)" ::: "memory");
      __hip_atomic_store(&flags[prev % 6], prev + 1, __ATOMIC_RELAXED,
                         __HIP_MEMORY_SCOPE_WORKGROUP);
    }
  } else {
    // ---- consumer: the serial recurrence ----
    const int d = lane >> 4;
    const int c = lane & 15;
    const bool d1 = (d & 1), d2 = (d & 2);
    const int pb = lane & 48;

    float4 hq;
    if (chunk == 0) {
      hq = *(const float4*)(init_hidden + 4 * c);
      float ss0 = row_sum16(hq.x * hq.x + hq.y * hq.y + hq.z * hq.z + hq.w * hq.w);
      float iv0 = 1.0f / fmaxf(sqrtf(ss0), 1e-12f);
      hq.x *= iv0; hq.y *= iv0; hq.z *= iv0; hq.w *= iv0;
    } else {
      hq = *(const float4*)(hstate + b * DS + 4 * c);
    }
    float inv_prev = 1.0f;

    float* outp = out + ((size_t)b * S_ + s_base) * DS + 4 * c;
    int fpre = -1;
    for (int s = 0; s < SC; ++s) {
      const int slot = s % 6;
      if (lane == 0 && (s & 7) == 0)
        __hip_atomic_store(&progress[b], s, __ATOMIC_RELAXED,
                           __HIP_MEMORY_SCOPE_AGENT);
      if (fpre < s + 1) {
        while (__hip_atomic_load(&flags[slot], __ATOMIC_ACQUIRE,
                                 __HIP_MEMORY_SCOPE_WORKGROUP) < s + 1)
          __builtin_amdgcn_s_sleep(0);
      }
      fpre = __hip_atomic_load(&flags[(s + 1) % 6], __ATOMIC_ACQUIRE,
                               __HIP_MEMORY_SCOPE_WORKGROUP);

      float hsel = d2 ? (d1 ? hq.w : hq.z) : (d1 ? hq.y : hq.x);
      float ax = 0.f, ay = 0.f, az = 0.f, aw = 0.f;
#pragma unroll
      for (int q = 0; q < 16; ++q) {
        float4 t4 = ring[slot][q][lane];
        float hb = __shfl(hsel, pb + q, 64);
        ax += hb * t4.x; ay += hb * t4.y;
        az += hb * t4.z; aw += hb * t4.w;
      }
      __hip_atomic_store(&cons, s + 1, __ATOMIC_RELAXED,
                         __HIP_MEMORY_SCOPE_WORKGROUP);

      ax += __shfl_xor(ax, 16, 64); ax += __shfl_xor(ax, 32, 64);
      ay += __shfl_xor(ay, 16, 64); ay += __shfl_xor(ay, 32, 64);
      az += __shfl_xor(az, 16, 64); az += __shfl_xor(az, 32, 64);
      aw += __shfl_xor(aw, 16, 64); aw += __shfl_xor(aw, 32, 64);
      hq.x = fmaxf(ax * inv_prev, 0.f);
      hq.y = fmaxf(ay * inv_prev, 0.f);
      hq.z = fmaxf(az * inv_prev, 0.f);
      hq.w = fmaxf(aw * inv_prev, 0.f);
      float ss = row_sum16(hq.x * hq.x + hq.y * hq.y + hq.z * hq.z + hq.w * hq.w);
      float inv = 1.0f / fmaxf(sqrtf(ss), 1e-12f);
      if (d == 0) {
        float4 o;
        o.x = hq.x * inv; o.y = hq.y * inv; o.z = hq.z * inv; o.w = hq.w * inv;
        *(float4*)(outp + (size_t)s * DS) = o;
      }
      inv_prev = inv;
    }
    if (d == 0) {
      float4 o;
      o.x = hq.x * inv_prev; o.y = hq.y * inv_prev;
      o.z = hq.z * inv_prev; o.w = hq.w * inv_prev;
      *(float4*)(hstate + b * DS + 4 * c) = o;
    }
    if (lane == 0)   // let prefetchers finish their tail quickly
      __hip_atomic_store(&progress[b], SC + 64, __ATOMIC_RELAXED,
                         __HIP_MEMORY_SCOPE_AGENT);
  }
}

// ---------------------------------------------------------------------------
extern "C" void kernel_launch(void* const* d_in, const int* in_sizes, int n_in,
                              void* d_out, int out_size, void* d_ws, size_t ws_size,
                              hipStream_t stream) {
  const float* actions     = (const float*)d_in[0];
  const float* w0          = (const float*)d_in[1];
  const float* b0          = (const float*)d_in[2];
  const float* w1          = (const float*)d_in[3];
  const float* b1          = (const float*)d_in[4];
  const float* w2          = (const float*)d_in[5];
  const float* b2          = (const float*)d_in[6];
  const float* init_hidden = (const float*)d_in[7];
  float* out = (float*)d_out;

  // pick the largest sequence chunk whose transitions fit in ws
  int SC = 2048;
  while (SC > 4) {
    size_t need = (size_t)SC * 32 * DS2 * 4   // transitions chunk
                + (size_t)SC * 32 * DH * 4    // h1t chunk
                + (size_t)B_ * DS * 4         // hidden-state carry (32 x 64!)
                + B_ * 4;                     // progress counters
    if (need <= ws_size) break;
    SC >>= 1;
  }
  float* trans    = (float*)d_ws;
  float* h1t      = trans + (size_t)SC * 32 * DS2;
  float* hstate   = h1t + (size_t)SC * 32 * DH;      // 32*64 floats
  int*   progress = (int*)(hstate + (size_t)B_ * DS); // AFTER full hstate

  const int M = SC * 32;
  const int nch = S_ / SC;
  for (int c = 0; c < nch; ++c) {
    int s_base = c * SC;
    hipLaunchKernelGGL(k_mlp01, dim3(M / 64), dim3(256), 0, stream,
                       actions, w0, b0, w1, b1, h1t, s_base, M);
    hipLaunchKernelGGL(k_trans, dim3(DS2 / 128, M / 128), dim3(256), 0, stream,
                       h1t, w2, b2, trans, M);
    hipLaunchKernelGGL(k_rnn, dim3(256), dim3(256), 0, stream,
                       trans, init_hidden, hstate, progress, out, s_base, SC, c);
  }
}

// Round 11
// 1630.189 us; speedup vs baseline: 1.6007x; 1.6007x over previous
//
#include <hip/hip_runtime.h>

// Problem constants
#define B_ 32
#define S_ 2048
#define DA 32
#define DH 128
#define DS 64
#define DS2 4096
#define TKK 16

template <int CTRL>
__device__ __forceinline__ float dpp_add(float x) {
  int t = __builtin_amdgcn_update_dpp(0, __float_as_int(x), CTRL, 0xF, 0xF, true);
  return x + __int_as_float(t);
}
// sum over the 16 lanes of each row, result uniform within the row
__device__ __forceinline__ float row_sum16(float x) {
  x = dpp_add<0xB1>(x);
  x = dpp_add<0x4E>(x);
  x = dpp_add<0x141>(x);
  x = dpp_add<0x140>(x);
  return x;
}

// async global->LDS DMA, 16 B per lane (dest = wave-uniform base + lane*16)
__device__ __forceinline__ void gl2lds16(const float* g, float* l) {
  __builtin_amdgcn_global_load_lds(
      (const __attribute__((address_space(1))) void*)g,
      (__attribute__((address_space(3))) void*)l, 16, 0, 0);
}

// ---------------------------------------------------------------------------
// Shared-memory union: rnn ring (96 KB) / trans staging (32 KB) / mlp (56 KB)
// 99 KB total -> exactly 1 block/CU -> 256 blocks map 1:1 onto 256 CUs.
// ---------------------------------------------------------------------------
struct SharedRnn {
  float4 ring[6][16][64];   // 96 KB
  int flags[6];
  int cons;
};
struct SharedGemm {
  float As[2][TKK][128];    // 16 KB
  float Bs[2][TKK][128];    // 16 KB
};
struct SharedMlp {
  float a_t[DA][64];        // 8 KB
  float w0_l[DA][DH];       // 16 KB
  float h0t[DH][64];        // 32 KB
};
union SharedU {
  SharedRnn r;
  SharedGemm g;
  SharedMlp m;
};

// ---------------------------------------------------------------------------
// MLP tile (validated R6 k_mlp01 body): 64 tokens -> h1t[f][tok] (transposed)
// ---------------------------------------------------------------------------
__device__ __forceinline__ void mlp_tile(
    const float* __restrict__ actions, const float* __restrict__ w0,
    const float* __restrict__ b0, const float* __restrict__ w1,
    const float* __restrict__ b1, float* __restrict__ h1t,
    int s_base, int M, int m0, SharedMlp& sm, int tid)
{
#pragma unroll
  for (int q = 0; q < 2; ++q) {
    int g = tid + 256 * q;
    int tok = g >> 3, kq = g & 7;
    int tl = m0 + tok;
    int b = tl & 31, s = s_base + (tl >> 5);
    float4 v = *(const float4*)(actions + ((size_t)b * S_ + s) * DA + 4 * kq);
    sm.a_t[4 * kq + 0][tok] = v.x; sm.a_t[4 * kq + 1][tok] = v.y;
    sm.a_t[4 * kq + 2][tok] = v.z; sm.a_t[4 * kq + 3][tok] = v.w;
  }
#pragma unroll
  for (int q = 0; q < 4; ++q) {
    int g = tid + 256 * q;
    ((float4*)&sm.w0_l[0][0])[g] = ((const float4*)w0)[g];
  }
  __syncthreads();

  const int tm = tid & 15;
  const int tn = tid >> 4;

  float acc[4][8];
#pragma unroll
  for (int mi = 0; mi < 4; ++mi)
#pragma unroll
    for (int ni = 0; ni < 8; ++ni) acc[mi][ni] = 0.f;

#pragma unroll 4
  for (int k = 0; k < DA; ++k) {
    float4 a4 = *(const float4*)&sm.a_t[k][4 * tm];
    float4 wa = *(const float4*)&sm.w0_l[k][8 * tn];
    float4 wb = *(const float4*)&sm.w0_l[k][8 * tn + 4];
    float av[4] = {a4.x, a4.y, a4.z, a4.w};
    float wv[8] = {wa.x, wa.y, wa.z, wa.w, wb.x, wb.y, wb.z, wb.w};
#pragma unroll
    for (int mi = 0; mi < 4; ++mi)
#pragma unroll
      for (int ni = 0; ni < 8; ++ni) acc[mi][ni] += av[mi] * wv[ni];
  }
  {
    float4 ba = *(const float4*)(b0 + 8 * tn);
    float4 bb = *(const float4*)(b0 + 8 * tn + 4);
    float bv[8] = {ba.x, ba.y, ba.z, ba.w, bb.x, bb.y, bb.z, bb.w};
#pragma unroll
    for (int mi = 0; mi < 4; ++mi)
#pragma unroll
      for (int ni = 0; ni < 8; ++ni)
        sm.h0t[8 * tn + ni][4 * tm + mi] = fmaxf(acc[mi][ni] + bv[ni], 0.f);
  }
  __syncthreads();

  float acc1[4][8];
#pragma unroll
  for (int mi = 0; mi < 4; ++mi)
#pragma unroll
    for (int ni = 0; ni < 8; ++ni) acc1[mi][ni] = 0.f;

#pragma unroll 4
  for (int k = 0; k < DH; ++k) {
    float4 h4 = *(const float4*)&sm.h0t[k][4 * tm];
    float4 wa = *(const float4*)(w1 + (size_t)k * DH + 8 * tn);
    float4 wb = *(const float4*)(w1 + (size_t)k * DH + 8 * tn + 4);
    float av[4] = {h4.x, h4.y, h4.z, h4.w};
    float wv[8] = {wa.x, wa.y, wa.z, wa.w, wb.x, wb.y, wb.z, wb.w};
#pragma unroll
    for (int mi = 0; mi < 4; ++mi)
#pragma unroll
      for (int ni = 0; ni < 8; ++ni) acc1[mi][ni] += av[mi] * wv[ni];
  }
  {
    float4 ba = *(const float4*)(b1 + 8 * tn);
    float4 bb = *(const float4*)(b1 + 8 * tn + 4);
    float bv[8] = {ba.x, ba.y, ba.z, ba.w, bb.x, bb.y, bb.z, bb.w};
#pragma unroll
    for (int ni = 0; ni < 8; ++ni) {
      float4 o;
      o.x = fmaxf(acc1[0][ni] + bv[ni], 0.f);
      o.y = fmaxf(acc1[1][ni] + bv[ni], 0.f);
      o.z = fmaxf(acc1[2][ni] + bv[ni], 0.f);
      o.w = fmaxf(acc1[3][ni] + bv[ni], 0.f);
      *(float4*)(h1t + (size_t)(8 * tn + ni) * M + m0 + 4 * tm) = o;
    }
  }
}

// ---------------------------------------------------------------------------
// Trans tile (validated R6 k_trans body): 128x128 output tile at (m0, n0)
// ---------------------------------------------------------------------------
__device__ __forceinline__ void trans_tile(
    const float* __restrict__ h1t, const float* __restrict__ w2,
    const float* __restrict__ b2, float* __restrict__ trans,
    int M, int n0, int m0, SharedGemm& sg, int tid)
{
  const int w  = tid >> 6;
  const int lw = tid & 63;

  auto aload = [&](int t, int buf) {
#pragma unroll
    for (int ii = 0; ii < 2; ++ii) {
      const int i = 2 * w + ii;
      const int kr = 2 * i + (lw >> 5);
      const int c4 = 4 * (lw & 31);
      gl2lds16(h1t + (size_t)(t * TKK + kr) * M + m0 + c4, &sg.As[buf][2 * i][0]);
      gl2lds16(w2 + (size_t)(t * TKK + kr) * DS2 + n0 + c4, &sg.Bs[buf][2 * i][0]);
    }
  };

  aload(0, 0);

  const int mg = tid >> 4;
  const int ng = tid & 15;
  float acc[8][8];
#pragma unroll
  for (int mi = 0; mi < 8; ++mi)
#pragma unroll
    for (int ni = 0; ni < 8; ++ni) acc[mi][ni] = 0.f;

  int buf = 0;
  for (int t = 0; t < DH / TKK; ++t) {
    __syncthreads();
    if (t < DH / TKK - 1) aload(t + 1, buf ^ 1);
#pragma unroll
    for (int k = 0; k < TKK; ++k) {
      float4 a0 = *(const float4*)&sg.As[buf][k][8 * mg];
      float4 a1 = *(const float4*)&sg.As[buf][k][8 * mg + 4];
      float av[8] = {a0.x, a0.y, a0.z, a0.w, a1.x, a1.y, a1.z, a1.w};
      float4 b0v = *(const float4*)&sg.Bs[buf][k][4 * ng];
      float4 b1v = *(const float4*)&sg.Bs[buf][k][64 + 4 * ng];
      float bv[8] = {b0v.x, b0v.y, b0v.z, b0v.w, b1v.x, b1v.y, b1v.z, b1v.w};
#pragma unroll
      for (int mi = 0; mi < 8; ++mi)
#pragma unroll
        for (int ni = 0; ni < 8; ++ni) acc[mi][ni] += av[mi] * bv[ni];
    }
    buf ^= 1;
  }

  float4 bb0 = *(const float4*)(b2 + n0 + 4 * ng);
  float4 bb1 = *(const float4*)(b2 + n0 + 64 + 4 * ng);
  float bv[8] = {bb0.x, bb0.y, bb0.z, bb0.w, bb1.x, bb1.y, bb1.z, bb1.w};
#pragma unroll
  for (int mi = 0; mi < 8; ++mi) {
    float* dst = trans + (size_t)(m0 + 8 * mg + mi) * DS2 + n0;
#pragma unroll
    for (int q = 0; q < 2; ++q) {
      float4 o;
      o.x = acc[mi][4 * q + 0] + bv[4 * q + 0];
      o.y = acc[mi][4 * q + 1] + bv[4 * q + 1];
      o.z = acc[mi][4 * q + 2] + bv[4 * q + 2];
      o.w = acc[mi][4 * q + 3] + bv[4 * q + 3];
      *(float4*)(dst + 64 * q + 4 * ng) = o;
    }
  }
}

// ---------------------------------------------------------------------------
// Standalone MLP kernel (chunk 0 priming)
// ---------------------------------------------------------------------------
__global__ __launch_bounds__(256) void k_mlp01(
    const float* __restrict__ actions, const float* __restrict__ w0,
    const float* __restrict__ b0, const float* __restrict__ w1,
    const float* __restrict__ b1, float* __restrict__ h1t,
    int s_base, int M)
{
  __shared__ SharedMlp sm;
  mlp_tile(actions, w0, b0, w1, b1, h1t, s_base, M, blockIdx.x * 64, sm,
           threadIdx.x);
}

// ---------------------------------------------------------------------------
// Combined pipelined kernel, launch index c = 0..nch:
//  blocks 0..31  : rnn for chunk c-1 (if c>0), reading trans[(c-1)%2]
//  blocks 32..255: trans tiles for chunk c (if c<nch): h1t[c%2] -> trans[c%2],
//                  then mlp tiles for chunk c+1 (if c+1<nch) -> h1t[(c+1)%2]
// ALL dependencies are cross-launch (stream-ordered); no cross-block sync.
// 99 KB shared union -> 1 block/CU -> exact 1:1 block:CU placement.
// ---------------------------------------------------------------------------
__global__ __launch_bounds__(256, 1) void k_comb(
    const float* __restrict__ actions, const float* __restrict__ w0,
    const float* __restrict__ b0, const float* __restrict__ w1,
    const float* __restrict__ b1, const float* __restrict__ w2,
    const float* __restrict__ b2, const float* __restrict__ init_hidden,
    float* __restrict__ trans0, float* __restrict__ trans1,
    float* __restrict__ h1t0, float* __restrict__ h1t1,
    float* __restrict__ hstate, float* __restrict__ out,
    int c, int SC, int nch)
{
  __shared__ SharedU sh;
  const int tid = threadIdx.x;
  const int M = SC * 32;

  if (blockIdx.x >= 32) {
    // -------------------- GEMM blocks --------------------
    const int bi = blockIdx.x - 32;   // 0..223
    if (c < nch) {
      const float* h1t = (c & 1) ? h1t1 : h1t0;
      float* trans = (c & 1) ? trans1 : trans0;
      const int NJ = (M / 128) * (DS2 / 128);
      for (int j = bi; j < NJ; j += 224) {
        const int mt = j >> 5, nt = j & 31;
        trans_tile(h1t, w2, b2, trans, M, nt * 128, mt * 128, sh.g, tid);
        __syncthreads();
      }
      if (c + 1 < nch) {
        __syncthreads();
        float* h1n = ((c + 1) & 1) ? h1t1 : h1t0;
        for (int j = bi; j < M / 64; j += 224) {
          mlp_tile(actions, w0, b0, w1, b1, h1n, (c + 1) * SC, M, j * 64,
                   sh.m, tid);
          __syncthreads();
        }
      }
    }
    return;
  }

  // -------------------- RNN blocks (chunk c-1), R8-validated --------------
  if (c == 0) return;
  const int cc = c - 1;               // rnn chunk index
  const float* trans = (cc & 1) ? trans1 : trans0;
  const int s_base = cc * SC;
  const int wv = tid >> 6;
  const int lane = tid & 63;
  const int b = blockIdx.x;

  if (tid < 6) sh.r.flags[tid] = 0;
  if (tid == 6) sh.r.cons = 0;
  __syncthreads();

  const float* base = trans + (size_t)b * DS2;

  if (wv > 0) {
    // producer: steps s ≡ wv-1 (mod 3)
    const int p = wv - 1;
    int prev = -1;
    for (int s = p; s < SC; s += 3) {
      while (s - __hip_atomic_load(&sh.r.cons, __ATOMIC_RELAXED,
                                   __HIP_MEMORY_SCOPE_WORKGROUP) > 5)
        __builtin_amdgcn_s_sleep(2);
      const int slot = s % 6;
      const float* g = base + (size_t)s * (32 * DS2) + 4 * lane;
      float* l = (float*)&sh.r.ring[slot][0][0];
#pragma unroll
      for (int q = 0; q < 16; ++q)
        gl2lds16(g + q * 256, l + q * 256);
      if (prev >= 0) {
        asm volatile("s_waitcnt vmcnt(16)" ::: "memory");
        __hip_atomic_store(&sh.r.flags[prev % 6], prev + 1, __ATOMIC_RELAXED,
                           __HIP_MEMORY_SCOPE_WORKGROUP);
      }
      prev = s;
    }
    if (prev >= 0) {
      asm volatile("s_waitcnt vmcnt(0)" ::: "memory");
      __hip_atomic_store(&sh.r.flags[prev % 6], prev + 1, __ATOMIC_RELAXED,
                         __HIP_MEMORY_SCOPE_WORKGROUP);
    }
  } else {
    // consumer: serial recurrence
    const int d = lane >> 4;
    const int cq = lane & 15;
    const bool d1 = (d & 1), d2 = (d & 2);
    const int pb = lane & 48;

    float4 hq;
    if (cc == 0) {
      hq = *(const float4*)(init_hidden + 4 * cq);
      float ss0 = row_sum16(hq.x * hq.x + hq.y * hq.y + hq.z * hq.z + hq.w * hq.w);
      float iv0 = 1.0f / fmaxf(sqrtf(ss0), 1e-12f);
      hq.x *= iv0; hq.y *= iv0; hq.z *= iv0; hq.w *= iv0;
    } else {
      hq = *(const float4*)(hstate + b * DS + 4 * cq);
    }
    float inv_prev = 1.0f;

    float* outp = out + ((size_t)b * S_ + s_base) * DS + 4 * cq;
    int fpre = -1;
    for (int s = 0; s < SC; ++s) {
      const int slot = s % 6;
      if (fpre < s + 1) {
        while (__hip_atomic_load(&sh.r.flags[slot], __ATOMIC_ACQUIRE,
                                 __HIP_MEMORY_SCOPE_WORKGROUP) < s + 1)
          __builtin_amdgcn_s_sleep(0);
      }
      fpre = __hip_atomic_load(&sh.r.flags[(s + 1) % 6], __ATOMIC_ACQUIRE,
                               __HIP_MEMORY_SCOPE_WORKGROUP);

      float hsel = d2 ? (d1 ? hq.w : hq.z) : (d1 ? hq.y : hq.x);
      float ax = 0.f, ay = 0.f, az = 0.f, aw = 0.f;
#pragma unroll
      for (int q = 0; q < 16; ++q) {
        float4 t4 = sh.r.ring[slot][q][lane];
        float hb = __shfl(hsel, pb + q, 64);
        ax += hb * t4.x; ay += hb * t4.y;
        az += hb * t4.z; aw += hb * t4.w;
      }
      __hip_atomic_store(&sh.r.cons, s + 1, __ATOMIC_RELAXED,
                         __HIP_MEMORY_SCOPE_WORKGROUP);

      ax += __shfl_xor(ax, 16, 64); ax += __shfl_xor(ax, 32, 64);
      ay += __shfl_xor(ay, 16, 64); ay += __shfl_xor(ay, 32, 64);
      az += __shfl_xor(az, 16, 64); az += __shfl_xor(az, 32, 64);
      aw += __shfl_xor(aw, 16, 64); aw += __shfl_xor(aw, 32, 64);
      hq.x = fmaxf(ax * inv_prev, 0.f);
      hq.y = fmaxf(ay * inv_prev, 0.f);
      hq.z = fmaxf(az * inv_prev, 0.f);
      hq.w = fmaxf(aw * inv_prev, 0.f);
      float ss = row_sum16(hq.x * hq.x + hq.y * hq.y + hq.z * hq.z + hq.w * hq.w);
      float inv = 1.0f / fmaxf(sqrtf(ss), 1e-12f);
      if (d == 0) {
        float4 o;
        o.x = hq.x * inv; o.y = hq.y * inv; o.z = hq.z * inv; o.w = hq.w * inv;
        *(float4*)(outp + (size_t)s * DS) = o;
      }
      inv_prev = inv;
    }
    if (d == 0) {
      float4 o;   // carry NORMALIZED state across chunks
      o.x = hq.x * inv_prev; o.y = hq.y * inv_prev;
      o.z = hq.z * inv_prev; o.w = hq.w * inv_prev;
      *(float4*)(hstate + b * DS + 4 * cq) = o;
    }
  }
}

// ---------------------------------------------------------------------------
extern "C" void kernel_launch(void* const* d_in, const int* in_sizes, int n_in,
                              void* d_out, int out_size, void* d_ws, size_t ws_size,
                              hipStream_t stream) {
  const float* actions     = (const float*)d_in[0];
  const float* w0          = (const float*)d_in[1];
  const float* b0          = (const float*)d_in[2];
  const float* w1          = (const float*)d_in[3];
  const float* b1          = (const float*)d_in[4];
  const float* w2          = (const float*)d_in[5];
  const float* b2          = (const float*)d_in[6];
  const float* init_hidden = (const float*)d_in[7];
  float* out = (float*)d_out;

  // largest chunk whose DOUBLE-buffered workspace fits
  int SC = 2048;
  while (SC > 4) {
    size_t need = 2 * ((size_t)SC * 32 * DS2 * 4 + (size_t)SC * 32 * DH * 4)
                + (size_t)B_ * DS * 4;
    if (need <= ws_size) break;
    SC >>= 1;
  }
  float* trans0 = (float*)d_ws;
  float* trans1 = trans0 + (size_t)SC * 32 * DS2;
  float* h1t0   = trans1 + (size_t)SC * 32 * DS2;
  float* h1t1   = h1t0 + (size_t)SC * 32 * DH;
  float* hstate = h1t1 + (size_t)SC * 32 * DH;

  const int M = SC * 32;
  const int nch = S_ / SC;

  // prime: mlp for chunk 0 -> h1t0
  hipLaunchKernelGGL(k_mlp01, dim3(M / 64), dim3(256), 0, stream,
                     actions, w0, b0, w1, b1, h1t0, 0, M);
  // pipelined combined launches
  for (int c = 0; c <= nch; ++c) {
    hipLaunchKernelGGL(k_comb, dim3(256), dim3(256), 0, stream,
                       actions, w0, b0, w1, b1, w2, b2, init_hidden,
                       trans0, trans1, h1t0, h1t1, hstate, out, c, SC, nch);
  }
}